// Round 14
// baseline (120.624 us; speedup 1.0000x reference)
//
#include <hip/hip_runtime.h>
#include <hip/hip_bf16.h>
#include <cstdint>
#include <cstddef>

// ---------------------------------------------------------------------------
// ResiduesNetwork: 2-layer GNN per protein + all-pairs MLP.
// Structure (6 nodes): conv_agg -> gemm_l1 -> agg1(combine4) -> gemm_l2 ->
// gemm_dual(inline combine+relu) -> pair.  GNN agg in INPUT space.
// R14: pair IBLK 2->4 (W LDS fragments amortize over 4 i's; pair was
// LDS-read-bound: 384 ds_read_b128/wave ~ 19us floor -> 256 ~ 13us).
// R13: gemm_l1 bx=1 (Z read once) + named double-buffer register pipeline.
// HISTORY: (a) launch_bounds min-waves forcing spilled breg (R3/R6) — never
// cap VGPR below demand. (b) cooperative mega-kernel (R8, 404us). (c) array-
// batch loads (R12): compiler collapses them — use distinct NAMED buffers.
// ---------------------------------------------------------------------------

typedef __bf16 bf16_t;
typedef __bf16 bf16x4 __attribute__((ext_vector_type(4)));
typedef __bf16 bf16x8 __attribute__((ext_vector_type(8)));
typedef float f32x4 __attribute__((ext_vector_type(4)));
typedef _Float16 f16_t;
typedef _Float16 f16x8 __attribute__((ext_vector_type(8)));

static __device__ __forceinline__ f32x4 mfma_bf16(bf16x8 a, bf16x8 b, f32x4 c) {
  return __builtin_amdgcn_mfma_f32_16x16x32_bf16(a, b, c, 0, 0, 0);
}
static __device__ __forceinline__ f32x4 mfma_f16(f16x8 a, f16x8 b, f32x4 c) {
  return __builtin_amdgcn_mfma_f32_16x16x32_f16(a, b, c, 0, 0, 0);
}

#define N1R 800
#define NR  1600   // concat rows
#define VF  1024
#define F0  256    // conv0 out
#define F1  128    // conv1 out

// split f32 -> (hi bf16x8, lo bf16x8) from two float4
static __device__ __forceinline__ void split8(float4 va, float4 vb,
                                              bf16x8& h8, bf16x8& l8) {
  float v[8] = {va.x, va.y, va.z, va.w, vb.x, vb.y, vb.z, vb.w};
  #pragma unroll
  for (int e = 0; e < 8; ++e) {
    bf16_t h = (bf16_t)v[e];
    h8[e] = h;
    l8[e] = (bf16_t)(v[e] - (float)h);
  }
}

// ---- fused: weight conversion/transpose + fbw + input-space aggregation ----
// grid.x: [0,2625) weight jobs; [2625,4225) agg0 rows (Zagg = gatherZ/cnt).
__global__ void conv_agg(const float* __restrict__ Z1, const float* __restrict__ Z2,
                         const int* __restrict__ nb1, const int* __restrict__ nb2,
                         const float* __restrict__ Wr0, const float* __restrict__ Wnr0,
                         const float* __restrict__ Wr1, const float* __restrict__ Wnr1,
                         const float* __restrict__ fW0, const float* __restrict__ fW1,
                         const float* __restrict__ fb1, const float* __restrict__ fW2,
                         const float* __restrict__ fb2,
                         bf16_t* __restrict__ W0h, bf16_t* __restrict__ W0l,
                         bf16_t* __restrict__ W1h, bf16_t* __restrict__ W1l,
                         bf16_t* __restrict__ fAh, bf16_t* __restrict__ fAl,
                         bf16_t* __restrict__ fBh, bf16_t* __restrict__ fBl,
                         f16_t* __restrict__ fW1th, float* __restrict__ fbw,
                         bf16_t* __restrict__ Zah, bf16_t* __restrict__ Zal) {
  int wb = blockIdx.x;
  int tid = threadIdx.x;
  if (wb >= 2625) {  // ---- agg0: Zagg[r] = (sum_nb Z[nb])/cnt, bf16 hi/lo ----
    int r = wb - 2625;
    const int* nbp;
    const float* Zp;
    if (r < N1R) { nbp = nb1 + r * 10; Zp = Z1; }
    else         { nbp = nb2 + (r - N1R) * 10; Zp = Z2; }
    int c4 = tid * 4;
    float4 s = make_float4(0.f, 0.f, 0.f, 0.f);
    int cnt = 0;
    #pragma unroll
    for (int k = 0; k < 10; ++k) {
      int idx = nbp[k];
      if (idx > -1) {
        cnt++;
        float4 v = *(const float4*)(Zp + (size_t)idx * VF + c4);
        s.x += v.x; s.y += v.y; s.z += v.z; s.w += v.w;
      }
    }
    float inv = 1.f / (float)(cnt > 0 ? cnt : 1);
    float vv[4] = {s.x * inv, s.y * inv, s.z * inv, s.w * inv};
    bf16x4 h4, l4;
    #pragma unroll
    for (int e = 0; e < 4; ++e) {
      bf16_t h = (bf16_t)vv[e];
      h4[e] = h;
      l4[e] = (bf16_t)(vv[e] - (float)h);
    }
    *(bf16x4*)(Zah + (size_t)r * VF + c4) = h4;
    *(bf16x4*)(Zal + (size_t)r * VF + c4) = l4;
    return;
  }
  if (wb >= 2560 && wb < 2624) {  // fW1 [256][64] -> f16 transposed [64][256]
    int t = (wb - 2560) * 256 + tid;
    int n = t & 63;
    int k = t >> 6;
    fW1th[(n << 8) + k] = (f16_t)fW1[k * 64 + n];
    return;
  }
  if (wb == 2624) {  // epilogue-constant table: fbw[jl*8+s]=fb1/fW2 slices
    if (tid < 128) {
      int jl = tid & 15, s = tid >> 4;
      fbw[jl * 8 + s] = (s < 4) ? fb1[s * 16 + jl] : fW2[(s - 4) * 16 + jl];
    } else if (tid == 128) {
      fbw[128] = fb2[0];
    }
    return;
  }
  const float* src; bf16_t* dh; bf16_t* dl; int ld, lk, ln, b0;
  if      (wb < 1024) { src = Wr0;  ld = 256; lk = 10; ln = 8; dh = W0h;              dl = W0l;              b0 = 0;    }
  else if (wb < 2048) { src = Wnr0; ld = 256; lk = 10; ln = 8; dh = W0h + 256 * 1024; dl = W0l + 256 * 1024; b0 = 1024; }
  else if (wb < 2176) { src = Wr1;  ld = 128; lk = 8;  ln = 7; dh = W1h;              dl = W1l;              b0 = 2048; }
  else if (wb < 2304) { src = Wnr1; ld = 128; lk = 8;  ln = 7; dh = W1h + 128 * 256;  dl = W1l + 128 * 256;  b0 = 2176; }
  else if (wb < 2432) { src = fW0;             ld = 256; lk = 7; ln = 8; dh = fAh;    dl = fAl;              b0 = 2304; }
  else                { src = fW0 + 128 * 256; ld = 256; lk = 7; ln = 8; dh = fBh;    dl = fBl;              b0 = 2432; }
  int t = (wb - b0) * 256 + tid;
  int n = t & ((1 << ln) - 1);
  int k = t >> ln;
  float v = src[k * ld + n];
  bf16_t h = (bf16_t)v;
  dh[(n << lk) + k] = h;
  dl[(n << lk) + k] = (bf16_t)(v - (float)h);
}

// consume one staged batch: 12 MFMA on 4 chains
#define CONSUME_F32(ZA, ZB, BH, BL)                      \
  { bf16x8 ah_, al_; split8(ZA, ZB, ah_, al_);           \
    _Pragma("unroll")                                    \
    for (int cf = 0; cf < 4; ++cf) {                     \
      acc[cf] = mfma_bf16(ah_, BH[cf], acc[cf]);         \
      acc[cf] = mfma_bf16(al_, BH[cf], acc[cf]);         \
      acc[cf] = mfma_bf16(ah_, BL[cf], acc[cf]);         \
    } }

#define CONSUME_BF16(AH, AL, BH, BL)                     \
  { _Pragma("unroll")                                    \
    for (int cf = 0; cf < 4; ++cf) {                     \
      acc[cf] = mfma_bf16(AH, BH[cf], acc[cf]);          \
      acc[cf] = mfma_bf16(AL, BH[cf], acc[cf]);          \
      acc[cf] = mfma_bf16(AH, BL[cf], acc[cf]);          \
    } }

// ---- layer-1 GEMM, split-K4, bx=1: P[z][1600][256] -------------------------
// z: half=z>>1 (0: Z@Wr0t, 1: Zagg@Wnr0t), kc=z&1 -> kStart=kc*512.
// grid (100, 4); block = 16 rows x 256 cols; wave = 16x64 (4 acc chains).
// Named double-buffer register pipeline: consume0/load0+64/consume1/load1+96.
__global__ __launch_bounds__(256) void gemm_l1(
    const float* __restrict__ Z1, const float* __restrict__ Z2,
    const bf16_t* __restrict__ Zah, const bf16_t* __restrict__ Zal,
    const bf16_t* __restrict__ W0h, const bf16_t* __restrict__ W0l,
    float* __restrict__ P) {
  int lane = threadIdx.x & 63;
  int w = threadIdx.x >> 6;
  int jl = lane & 15, hi = lane >> 4;

  int row0 = blockIdx.x * 16;
  int z = blockIdx.y;
  int half = z >> 1;
  int kStart = (z & 1) * 512;
  int r = row0 + jl;

  const size_t WOFF = (size_t)half * 256 * 1024;
  const bf16_t* pBh[4];
  const bf16_t* pBl[4];
  #pragma unroll
  for (int cf = 0; cf < 4; ++cf) {
    int col = w * 64 + cf * 16 + jl;
    pBh[cf] = W0h + WOFF + (size_t)col * 1024 + hi * 8 + kStart;
    pBl[cf] = W0l + WOFF + (size_t)col * 1024 + hi * 8 + kStart;
  }

  f32x4 acc[4] = {};

  if (half == 0) {
    const float* pZ = ((r < N1R) ? Z1 + (size_t)r * VF
                                 : Z2 + (size_t)(r - N1R) * VF) + hi * 8 + kStart;
    float4 za0, zb0, za1, zb1;
    bf16x8 bh0[4], bl0[4], bh1[4], bl1[4];
    za0 = *(const float4*)(pZ + 0);
    zb0 = *(const float4*)(pZ + 4);
    #pragma unroll
    for (int cf = 0; cf < 4; ++cf) {
      bh0[cf] = *(const bf16x8*)(pBh[cf] + 0);
      bl0[cf] = *(const bf16x8*)(pBl[cf] + 0);
    }
    za1 = *(const float4*)(pZ + 32);
    zb1 = *(const float4*)(pZ + 36);
    #pragma unroll
    for (int cf = 0; cf < 4; ++cf) {
      bh1[cf] = *(const bf16x8*)(pBh[cf] + 32);
      bl1[cf] = *(const bf16x8*)(pBl[cf] + 32);
    }
    #pragma unroll 1
    for (int it = 0; it < 7; ++it) {
      int kb = it * 64;
      CONSUME_F32(za0, zb0, bh0, bl0)
      za0 = *(const float4*)(pZ + kb + 64);
      zb0 = *(const float4*)(pZ + kb + 68);
      #pragma unroll
      for (int cf = 0; cf < 4; ++cf) {
        bh0[cf] = *(const bf16x8*)(pBh[cf] + kb + 64);
        bl0[cf] = *(const bf16x8*)(pBl[cf] + kb + 64);
      }
      CONSUME_F32(za1, zb1, bh1, bl1)
      za1 = *(const float4*)(pZ + kb + 96);
      zb1 = *(const float4*)(pZ + kb + 100);
      #pragma unroll
      for (int cf = 0; cf < 4; ++cf) {
        bh1[cf] = *(const bf16x8*)(pBh[cf] + kb + 96);
        bl1[cf] = *(const bf16x8*)(pBl[cf] + kb + 96);
      }
    }
    CONSUME_F32(za0, zb0, bh0, bl0)
    CONSUME_F32(za1, zb1, bh1, bl1)
  } else {
    const bf16_t* pAh = Zah + (size_t)r * VF + hi * 8 + kStart;
    const bf16_t* pAl = Zal + (size_t)r * VF + hi * 8 + kStart;
    bf16x8 ah0, al0, ah1, al1;
    bf16x8 bh0[4], bl0[4], bh1[4], bl1[4];
    ah0 = *(const bf16x8*)(pAh + 0);
    al0 = *(const bf16x8*)(pAl + 0);
    #pragma unroll
    for (int cf = 0; cf < 4; ++cf) {
      bh0[cf] = *(const bf16x8*)(pBh[cf] + 0);
      bl0[cf] = *(const bf16x8*)(pBl[cf] + 0);
    }
    ah1 = *(const bf16x8*)(pAh + 32);
    al1 = *(const bf16x8*)(pAl + 32);
    #pragma unroll
    for (int cf = 0; cf < 4; ++cf) {
      bh1[cf] = *(const bf16x8*)(pBh[cf] + 32);
      bl1[cf] = *(const bf16x8*)(pBl[cf] + 32);
    }
    #pragma unroll 1
    for (int it = 0; it < 7; ++it) {
      int kb = it * 64;
      CONSUME_BF16(ah0, al0, bh0, bl0)
      ah0 = *(const bf16x8*)(pAh + kb + 64);
      al0 = *(const bf16x8*)(pAl + kb + 64);
      #pragma unroll
      for (int cf = 0; cf < 4; ++cf) {
        bh0[cf] = *(const bf16x8*)(pBh[cf] + kb + 64);
        bl0[cf] = *(const bf16x8*)(pBl[cf] + kb + 64);
      }
      CONSUME_BF16(ah1, al1, bh1, bl1)
      ah1 = *(const bf16x8*)(pAh + kb + 96);
      al1 = *(const bf16x8*)(pAl + kb + 96);
      #pragma unroll
      for (int cf = 0; cf < 4; ++cf) {
        bh1[cf] = *(const bf16x8*)(pBh[cf] + kb + 96);
        bl1[cf] = *(const bf16x8*)(pBl[cf] + kb + 96);
      }
    }
    CONSUME_BF16(ah0, al0, bh0, bl0)
    CONSUME_BF16(ah1, al1, bh1, bl1)
  }

  float* Pz = P + (size_t)z * NR * F0;
  #pragma unroll
  for (int cf = 0; cf < 4; ++cf) {
    int col = w * 64 + cf * 16 + jl;
    #pragma unroll
    for (int reg = 0; reg < 4; ++reg) {
      int row = row0 + hi * 4 + reg;
      Pz[(size_t)row * F0 + col] = acc[cf][reg];
    }
  }
}

// ---- agg1 (+combine4): H0 = relu(sum P[0..3]); H0agg = gather(H0)/cnt -----
__global__ void agg1_kernel(const float* __restrict__ P,
                            const int* __restrict__ nb1, const int* __restrict__ nb2,
                            bf16_t* __restrict__ H0h, bf16_t* __restrict__ H0l,
                            bf16_t* __restrict__ Gah, bf16_t* __restrict__ Gal) {
  int r = blockIdx.x;
  int c = threadIdx.x;
  const size_t PS = (size_t)NR * F0;
  const int* nbp;
  int roff;
  if (r < N1R) { nbp = nb1 + r * 10; roff = 0; }
  else         { nbp = nb2 + (r - N1R) * 10; roff = N1R; }
  // own row
  size_t so = (size_t)r * F0 + c;
  float v = fmaxf(P[so] + P[so + PS] + P[so + 2 * PS] + P[so + 3 * PS], 0.f);
  bf16_t h = (bf16_t)v;
  H0h[so] = h;
  H0l[so] = (bf16_t)(v - (float)h);
  // gather
  float s = 0.f; int cnt = 0;
  #pragma unroll
  for (int k = 0; k < 10; ++k) {
    int idx = nbp[k];
    if (idx > -1) {
      cnt++;
      size_t o = (size_t)(roff + idx) * F0 + c;
      s += fmaxf(P[o] + P[o + PS] + P[o + 2 * PS] + P[o + 3 * PS], 0.f);
    }
  }
  float g = s / (float)(cnt > 0 ? cnt : 1);
  bf16_t gh = (bf16_t)g;
  Gah[so] = gh;
  Gal[so] = (bf16_t)(g - (float)gh);
}

// ---- layer-2 GEMM, split-K2, batched: P2[z][1600][128] (f32) --------------
// z=0: H0 @ Wr1t ; z=1: G @ Wnr1t.  grid (2, 100, 2); wave tile 16x16; K=256.
__global__ __launch_bounds__(256) void gemm_l2(
    const bf16_t* __restrict__ H0h, const bf16_t* __restrict__ H0l,
    const bf16_t* __restrict__ Gah, const bf16_t* __restrict__ Gal,
    const bf16_t* __restrict__ W1h, const bf16_t* __restrict__ W1l,
    float* __restrict__ P2) {
  int lane = threadIdx.x & 63;
  int w = threadIdx.x >> 6;
  int jl = lane & 15, hi = lane >> 4;

  int row0 = blockIdx.y * 16;
  int col = blockIdx.x * 64 + w * 16 + jl;
  int z = blockIdx.z;
  int r = row0 + jl;

  const bf16_t* pAh = (z ? Gah : H0h) + (size_t)r * F0 + hi * 8;
  const bf16_t* pAl = (z ? Gal : H0l) + (size_t)r * F0 + hi * 8;
  const size_t WOFF = (size_t)z * 128 * 256;
  const bf16_t* pBh = W1h + WOFF + (size_t)col * 256 + hi * 8;
  const bf16_t* pBl = W1l + WOFF + (size_t)col * 256 + hi * 8;

  f32x4 accE = {}, accO = {};
  for (int kb = 0; kb < 256; kb += 128) {
    bf16x8 ah[4], al[4], bh[4], bl[4];
    #pragma unroll
    for (int u = 0; u < 4; ++u) {
      ah[u] = *(const bf16x8*)(pAh + kb + u * 32);
      al[u] = *(const bf16x8*)(pAl + kb + u * 32);
      bh[u] = *(const bf16x8*)(pBh + kb + u * 32);
      bl[u] = *(const bf16x8*)(pBl + kb + u * 32);
    }
    #pragma unroll
    for (int u = 0; u < 4; ++u) {
      f32x4& acc = (u & 1) ? accO : accE;
      acc = mfma_bf16(ah[u], bh[u], acc);
      acc = mfma_bf16(al[u], bh[u], acc);
      acc = mfma_bf16(ah[u], bl[u], acc);
    }
  }
  float* Pz = P2 + (size_t)z * NR * F1;
  #pragma unroll
  for (int reg = 0; reg < 4; ++reg) {
    int row = row0 + hi * 4 + reg;
    Pz[(size_t)row * F1 + col] = accE[reg] + accO[reg];
  }
}

// ---- dual GEMM (inline combine+relu of P2): ABh = [A'|B] f16 --------------
// h1 = relu(P2_0 + P2_1) built in-register; grid (4, 100); K=128 fully batched.
__global__ __launch_bounds__(256) void gemm_dual(
    const float* __restrict__ P2,
    const bf16_t* __restrict__ fAh, const bf16_t* __restrict__ fAl,
    const bf16_t* __restrict__ fBh, const bf16_t* __restrict__ fBl,
    const float* __restrict__ fb0, f16_t* __restrict__ ABh) {
  int lane = threadIdx.x & 63;
  int w = threadIdx.x >> 6;
  int jl = lane & 15, hi = lane >> 4;

  int row0 = blockIdx.y * 16;
  int col = blockIdx.x * 64 + w * 16 + jl;
  int r = row0 + jl;
  bool isA = (row0 < N1R);

  const float* pP0 = P2 + (size_t)r * F1 + hi * 8;
  const float* pP1 = pP0 + (size_t)NR * F1;
  const bf16_t* pBh = (isA ? fAh : fBh) + (size_t)col * F1 + hi * 8;
  const bf16_t* pBl = (isA ? fAl : fBl) + (size_t)col * F1 + hi * 8;

  // batch the whole K=128: 16 float4 + 8 bf16x8 loads
  float4 p0[4][2], p1[4][2];
  bf16x8 bh[4], bl[4];
  #pragma unroll
  for (int u = 0; u < 4; ++u) {
    p0[u][0] = *(const float4*)(pP0 + u * 32);
    p0[u][1] = *(const float4*)(pP0 + u * 32 + 4);
    p1[u][0] = *(const float4*)(pP1 + u * 32);
    p1[u][1] = *(const float4*)(pP1 + u * 32 + 4);
    bh[u] = *(const bf16x8*)(pBh + u * 32);
    bl[u] = *(const bf16x8*)(pBl + u * 32);
  }
  f32x4 accE = {}, accO = {};
  #pragma unroll
  for (int u = 0; u < 4; ++u) {
    float4 s0 = make_float4(fmaxf(p0[u][0].x + p1[u][0].x, 0.f),
                            fmaxf(p0[u][0].y + p1[u][0].y, 0.f),
                            fmaxf(p0[u][0].z + p1[u][0].z, 0.f),
                            fmaxf(p0[u][0].w + p1[u][0].w, 0.f));
    float4 s1 = make_float4(fmaxf(p0[u][1].x + p1[u][1].x, 0.f),
                            fmaxf(p0[u][1].y + p1[u][1].y, 0.f),
                            fmaxf(p0[u][1].z + p1[u][1].z, 0.f),
                            fmaxf(p0[u][1].w + p1[u][1].w, 0.f));
    bf16x8 ah, al;
    split8(s0, s1, ah, al);
    f32x4& acc = (u & 1) ? accO : accE;
    acc = mfma_bf16(ah, bh[u], acc);
    acc = mfma_bf16(al, bh[u], acc);
    acc = mfma_bf16(ah, bl[u], acc);
  }

  float bv = isA ? fb0[col] : 0.f;
  #pragma unroll
  for (int reg = 0; reg < 4; ++reg) {
    int row = row0 + hi * 4 + reg;
    ABh[(size_t)row * 256 + col] = (f16_t)(accE[reg] + accO[reg] + bv);
  }
}

// ---- pair kernel (FP16): out = fb2 + relu(relu(A'+B)@fW1+fb1).fW2 ---------
// block: 64 j (4 waves x 16) x 16 i, i in groups of IBLK=4 (W LDS fragments
// amortize over 4 i's: 256 ds_read_b128/wave vs 384 at IBLK=2).
#define IBLK 4
#define ITILE 16
__global__ __launch_bounds__(256) void pair_kernel(
    const f16_t* __restrict__ ABh, const f16_t* __restrict__ W1th,
    const float* __restrict__ fbw, float* __restrict__ out) {
  __shared__ alignas(16) unsigned char sWh[64 * 512];   // [n][512B] swizzled
  __shared__ alignas(16) f16_t sA[ITILE * 256];         // 8KB

  const int tid = threadIdx.x;
  const int lane = tid & 63;
  const int w = tid >> 6;
  const int jl = lane & 15;
  const int hi = lane >> 4;
  const int j0 = blockIdx.x * 64;
  const int i0 = blockIdx.y * ITILE;

  // stage fW1t f16 [64][256] -> LDS, swizzle byte^=((n&7)<<4) in-row
  #pragma unroll
  for (int s = 0; s < 8; ++s) {
    int c = tid + 256 * s;
    int n = c >> 5;
    int cb = (c & 31) << 4;
    int sw = cb ^ ((n & 7) << 4);
    *(uint4*)(sWh + n * 512 + sw) = *(const uint4*)((const unsigned char*)W1th + n * 512 + cb);
  }
  // stage A' rows i0..i0+15 (f16): 512 x 16B chunks, 32 per row
  #pragma unroll
  for (int s = 0; s < 2; ++s) {
    int c = tid + 256 * s;
    int rr = c >> 5;
    int cc = c & 31;
    *(uint4*)((unsigned char*)sA + rr * 512 + cc * 16) =
        *(const uint4*)(ABh + (size_t)(i0 + rr) * 256 + cc * 8);
  }

  // B row of this lane's pair -> registers (its k-slice: 64 f16 = 32 VGPR)
  int j = j0 + w * 16 + jl;
  f16x8 breg[8];
  {
    const f16_t* Bp = ABh + (size_t)(N1R + j) * 256;
    bool ok = (j < N1R);
    f16x8 z{};
    #pragma unroll
    for (int t = 0; t < 8; ++t)
      breg[t] = ok ? *(const f16x8*)(Bp + t * 32 + hi * 8) : z;
  }

  // epilogue constants: 2 vector loads from pre-transposed table
  float4 fb1r = *(const float4*)(fbw + jl * 8);
  float4 fw2r = *(const float4*)(fbw + jl * 8 + 4);
  float bias2 = fbw[128];

  __syncthreads();

  #pragma unroll 1
  for (int ig = 0; ig < ITILE / IBLK; ++ig) {
    f32x4 acc[IBLK][4] = {};
    #pragma unroll
    for (int t = 0; t < 8; ++t) {
      f16x8 bv = breg[t];
      f16x8 af[IBLK];
      const f16x8 Zv{};
      #pragma unroll
      for (int ib = 0; ib < IBLK; ++ib) {
        f16x8 av = *(const f16x8*)(sA + (ig * IBLK + ib) * 256 + t * 32 + hi * 8);
        af[ib] = __builtin_elementwise_max(av + bv, Zv);  // pk_add + pk_max
      }
      int kbyte = t * 64 + hi * 16;
      #pragma unroll
      for (int nf = 0; nf < 4; ++nf) {
        int n = nf * 16 + jl;
        f16x8 wh = *(const f16x8*)(sWh + n * 512 + (kbyte ^ ((n & 7) << 4)));
        #pragma unroll
        for (int ib = 0; ib < IBLK; ++ib)
          acc[ib][nf] = mfma_f16(af[ib], wh, acc[ib][nf]);
      }
    }
    // epilogue: h1 = relu(acc + fb1); out = h1 . fW2 + fb2
    float fb1a[4] = {fb1r.x, fb1r.y, fb1r.z, fb1r.w};
    float fw2a[4] = {fw2r.x, fw2r.y, fw2r.z, fw2r.w};
    #pragma unroll
    for (int ib = 0; ib < IBLK; ++ib) {
      float part[4];
      #pragma unroll
      for (int r = 0; r < 4; ++r) {
        float ssum = 0.f;
        #pragma unroll
        for (int nf = 0; nf < 4; ++nf) {
          float h = acc[ib][nf][r] + fb1a[nf];
          h = fmaxf(h, 0.f);
          ssum += h * fw2a[nf];
        }
        part[r] = ssum;
      }
      #pragma unroll
      for (int off = 1; off < 16; off <<= 1) {
        #pragma unroll
        for (int r = 0; r < 4; ++r) part[r] += __shfl_xor(part[r], off, 64);
      }
      if (jl == 0) {
        int jo = j0 + w * 16 + hi * 4;
        if (jo < N1R) {
          float4 o = make_float4(part[0] + bias2, part[1] + bias2,
                                 part[2] + bias2, part[3] + bias2);
          *(float4*)(out + (size_t)(i0 + ig * IBLK + ib) * 800 + jo) = o;
        }
      }
    }
  }
}

// ---------------------------------------------------------------------------
extern "C" void kernel_launch(void* const* d_in, const int* in_sizes, int n_in,
                              void* d_out, int out_size, void* d_ws, size_t ws_size,
                              hipStream_t stream) {
  const float* Z1   = (const float*)d_in[0];
  const int*   nb1  = (const int*)d_in[1];
  const float* Z2   = (const float*)d_in[2];
  const int*   nb2  = (const int*)d_in[3];
  const float* Wr0  = (const float*)d_in[4];
  const float* Wnr0 = (const float*)d_in[5];
  const float* Wr1  = (const float*)d_in[6];
  const float* Wnr1 = (const float*)d_in[7];
  const float* fW0  = (const float*)d_in[8];
  const float* fb0  = (const float*)d_in[9];
  const float* fW1  = (const float*)d_in[10];
  const float* fb1  = (const float*)d_in[11];
  const float* fW2  = (const float*)d_in[12];
  const float* fb2  = (const float*)d_in[13];
  float* out = (float*)d_out;

  // workspace carve
  char* p = (char*)d_ws;
  auto alloc = [&](size_t bytes) {
    char* q = p;
    p += (bytes + 255) & ~(size_t)255;
    return q;
  };
  bf16_t* W0h   = (bf16_t*)alloc((size_t)512 * 1024 * 2);
  bf16_t* W0l   = (bf16_t*)alloc((size_t)512 * 1024 * 2);
  bf16_t* W1h   = (bf16_t*)alloc((size_t)256 * 256 * 2);
  bf16_t* W1l   = (bf16_t*)alloc((size_t)256 * 256 * 2);
  bf16_t* fAh   = (bf16_t*)alloc((size_t)256 * 128 * 2);
  bf16_t* fAl   = (bf16_t*)alloc((size_t)256 * 128 * 2);
  bf16_t* fBh   = (bf16_t*)alloc((size_t)256 * 128 * 2);
  bf16_t* fBl   = (bf16_t*)alloc((size_t)256 * 128 * 2);
  f16_t*  fW1th = (f16_t*)alloc((size_t)64 * 256 * 2);
  float*  fbw   = (float*)alloc(129 * 4);
  bf16_t* Zah   = (bf16_t*)alloc((size_t)NR * VF * 2);
  bf16_t* Zal   = (bf16_t*)alloc((size_t)NR * VF * 2);
  float*  P01   = (float*)alloc((size_t)4 * NR * F0 * 4);
  bf16_t* H0h   = (bf16_t*)alloc((size_t)NR * F0 * 2);
  bf16_t* H0l   = (bf16_t*)alloc((size_t)NR * F0 * 2);
  bf16_t* Gah   = (bf16_t*)alloc((size_t)NR * F0 * 2);
  bf16_t* Gal   = (bf16_t*)alloc((size_t)NR * F0 * 2);
  float*  P2    = (float*)alloc((size_t)2 * NR * F1 * 4);
  f16_t*  ABh   = (f16_t*)alloc((size_t)NR * 256 * 2);
  (void)in_sizes; (void)n_in; (void)out_size; (void)ws_size;

  // 1. weight conversion + fbw + input-space aggregation (one launch)
  conv_agg<<<4225, 256, 0, stream>>>(Z1, Z2, nb1, nb2, Wr0, Wnr0, Wr1, Wnr1,
                                     fW0, fW1, fb1, fW2, fb2,
                                     W0h, W0l, W1h, W1l, fAh, fAl, fBh, fBl,
                                     fW1th, fbw, Zah, Zal);
  // 2. layer-1 split-K4 GEMM (bx=1, Z read once) -> partials P[4][1600][256]
  gemm_l1<<<dim3(100, 4), 256, 0, stream>>>(Z1, Z2, Zah, Zal, W0h, W0l, P01);
  // 3. combine4 + relu + H0 aggregation (one launch)
  agg1_kernel<<<NR, 256, 0, stream>>>(P01, nb1, nb2, H0h, H0l, Gah, Gal);
  // 4. layer-2 split-K2 GEMM -> partials P2[2][1600][128]
  gemm_l2<<<dim3(2, 100, 2), 256, 0, stream>>>(H0h, H0l, Gah, Gal, W1h, W1l, P2);
  // 5. dual GEMM (inline combine+relu) -> ABh f16
  gemm_dual<<<dim3(4, 100), 256, 0, stream>>>(P2, fAh, fAl, fBh, fBl, fb0, ABh);
  // 6. all-pairs fused MLP (fp16 datapath)
  pair_kernel<<<dim3(13, 50), 256, 0, stream>>>(ABh, fW1th, fbw, out);
}

// Round 15
// 111.854 us; speedup vs baseline: 1.0784x; 1.0784x over previous
//
#include <hip/hip_runtime.h>
#include <hip/hip_bf16.h>
#include <cstdint>
#include <cstddef>

// ---------------------------------------------------------------------------
// ResiduesNetwork: 2-layer GNN per protein + all-pairs MLP.
// Structure (6 nodes): conv_agg -> gemm_l1 -> agg1(combine4) -> gemm_l2 ->
// gemm_dual(inline combine+relu) -> pair.  GNN agg in INPUT space.
// R15 = exact revert to R13 (session best, 112.0us): gemm_l1 bx=1 (Z read
// once) + named double-buffer register pipeline; pair IBLK=2.
// HISTORY: (a) launch_bounds min-waves forcing spilled breg (R3/R6) — never
// cap VGPR below demand. (b) cooperative mega-kernel (R8, 404us). (c) array-
// batch loads (R12): compiler collapses them — use distinct NAMED buffers.
// (d) pair IBLK=4 (R14): regressed 112->121us — register footprint beats
// LDS-read amortization at this size.
// ---------------------------------------------------------------------------

typedef __bf16 bf16_t;
typedef __bf16 bf16x4 __attribute__((ext_vector_type(4)));
typedef __bf16 bf16x8 __attribute__((ext_vector_type(8)));
typedef float f32x4 __attribute__((ext_vector_type(4)));
typedef _Float16 f16_t;
typedef _Float16 f16x8 __attribute__((ext_vector_type(8)));

static __device__ __forceinline__ f32x4 mfma_bf16(bf16x8 a, bf16x8 b, f32x4 c) {
  return __builtin_amdgcn_mfma_f32_16x16x32_bf16(a, b, c, 0, 0, 0);
}
static __device__ __forceinline__ f32x4 mfma_f16(f16x8 a, f16x8 b, f32x4 c) {
  return __builtin_amdgcn_mfma_f32_16x16x32_f16(a, b, c, 0, 0, 0);
}

#define N1R 800
#define NR  1600   // concat rows
#define VF  1024
#define F0  256    // conv0 out
#define F1  128    // conv1 out

// split f32 -> (hi bf16x8, lo bf16x8) from two float4
static __device__ __forceinline__ void split8(float4 va, float4 vb,
                                              bf16x8& h8, bf16x8& l8) {
  float v[8] = {va.x, va.y, va.z, va.w, vb.x, vb.y, vb.z, vb.w};
  #pragma unroll
  for (int e = 0; e < 8; ++e) {
    bf16_t h = (bf16_t)v[e];
    h8[e] = h;
    l8[e] = (bf16_t)(v[e] - (float)h);
  }
}

// ---- fused: weight conversion/transpose + fbw + input-space aggregation ----
// grid.x: [0,2625) weight jobs; [2625,4225) agg0 rows (Zagg = gatherZ/cnt).
__global__ void conv_agg(const float* __restrict__ Z1, const float* __restrict__ Z2,
                         const int* __restrict__ nb1, const int* __restrict__ nb2,
                         const float* __restrict__ Wr0, const float* __restrict__ Wnr0,
                         const float* __restrict__ Wr1, const float* __restrict__ Wnr1,
                         const float* __restrict__ fW0, const float* __restrict__ fW1,
                         const float* __restrict__ fb1, const float* __restrict__ fW2,
                         const float* __restrict__ fb2,
                         bf16_t* __restrict__ W0h, bf16_t* __restrict__ W0l,
                         bf16_t* __restrict__ W1h, bf16_t* __restrict__ W1l,
                         bf16_t* __restrict__ fAh, bf16_t* __restrict__ fAl,
                         bf16_t* __restrict__ fBh, bf16_t* __restrict__ fBl,
                         f16_t* __restrict__ fW1th, float* __restrict__ fbw,
                         bf16_t* __restrict__ Zah, bf16_t* __restrict__ Zal) {
  int wb = blockIdx.x;
  int tid = threadIdx.x;
  if (wb >= 2625) {  // ---- agg0: Zagg[r] = (sum_nb Z[nb])/cnt, bf16 hi/lo ----
    int r = wb - 2625;
    const int* nbp;
    const float* Zp;
    if (r < N1R) { nbp = nb1 + r * 10; Zp = Z1; }
    else         { nbp = nb2 + (r - N1R) * 10; Zp = Z2; }
    int c4 = tid * 4;
    float4 s = make_float4(0.f, 0.f, 0.f, 0.f);
    int cnt = 0;
    #pragma unroll
    for (int k = 0; k < 10; ++k) {
      int idx = nbp[k];
      if (idx > -1) {
        cnt++;
        float4 v = *(const float4*)(Zp + (size_t)idx * VF + c4);
        s.x += v.x; s.y += v.y; s.z += v.z; s.w += v.w;
      }
    }
    float inv = 1.f / (float)(cnt > 0 ? cnt : 1);
    float vv[4] = {s.x * inv, s.y * inv, s.z * inv, s.w * inv};
    bf16x4 h4, l4;
    #pragma unroll
    for (int e = 0; e < 4; ++e) {
      bf16_t h = (bf16_t)vv[e];
      h4[e] = h;
      l4[e] = (bf16_t)(vv[e] - (float)h);
    }
    *(bf16x4*)(Zah + (size_t)r * VF + c4) = h4;
    *(bf16x4*)(Zal + (size_t)r * VF + c4) = l4;
    return;
  }
  if (wb >= 2560 && wb < 2624) {  // fW1 [256][64] -> f16 transposed [64][256]
    int t = (wb - 2560) * 256 + tid;
    int n = t & 63;
    int k = t >> 6;
    fW1th[(n << 8) + k] = (f16_t)fW1[k * 64 + n];
    return;
  }
  if (wb == 2624) {  // epilogue-constant table: fbw[jl*8+s]=fb1/fW2 slices
    if (tid < 128) {
      int jl = tid & 15, s = tid >> 4;
      fbw[jl * 8 + s] = (s < 4) ? fb1[s * 16 + jl] : fW2[(s - 4) * 16 + jl];
    } else if (tid == 128) {
      fbw[128] = fb2[0];
    }
    return;
  }
  const float* src; bf16_t* dh; bf16_t* dl; int ld, lk, ln, b0;
  if      (wb < 1024) { src = Wr0;  ld = 256; lk = 10; ln = 8; dh = W0h;              dl = W0l;              b0 = 0;    }
  else if (wb < 2048) { src = Wnr0; ld = 256; lk = 10; ln = 8; dh = W0h + 256 * 1024; dl = W0l + 256 * 1024; b0 = 1024; }
  else if (wb < 2176) { src = Wr1;  ld = 128; lk = 8;  ln = 7; dh = W1h;              dl = W1l;              b0 = 2048; }
  else if (wb < 2304) { src = Wnr1; ld = 128; lk = 8;  ln = 7; dh = W1h + 128 * 256;  dl = W1l + 128 * 256;  b0 = 2176; }
  else if (wb < 2432) { src = fW0;             ld = 256; lk = 7; ln = 8; dh = fAh;    dl = fAl;              b0 = 2304; }
  else                { src = fW0 + 128 * 256; ld = 256; lk = 7; ln = 8; dh = fBh;    dl = fBl;              b0 = 2432; }
  int t = (wb - b0) * 256 + tid;
  int n = t & ((1 << ln) - 1);
  int k = t >> ln;
  float v = src[k * ld + n];
  bf16_t h = (bf16_t)v;
  dh[(n << lk) + k] = h;
  dl[(n << lk) + k] = (bf16_t)(v - (float)h);
}

// consume one staged batch: 12 MFMA on 4 chains
#define CONSUME_F32(ZA, ZB, BH, BL)                      \
  { bf16x8 ah_, al_; split8(ZA, ZB, ah_, al_);           \
    _Pragma("unroll")                                    \
    for (int cf = 0; cf < 4; ++cf) {                     \
      acc[cf] = mfma_bf16(ah_, BH[cf], acc[cf]);         \
      acc[cf] = mfma_bf16(al_, BH[cf], acc[cf]);         \
      acc[cf] = mfma_bf16(ah_, BL[cf], acc[cf]);         \
    } }

#define CONSUME_BF16(AH, AL, BH, BL)                     \
  { _Pragma("unroll")                                    \
    for (int cf = 0; cf < 4; ++cf) {                     \
      acc[cf] = mfma_bf16(AH, BH[cf], acc[cf]);          \
      acc[cf] = mfma_bf16(AL, BH[cf], acc[cf]);          \
      acc[cf] = mfma_bf16(AH, BL[cf], acc[cf]);          \
    } }

// ---- layer-1 GEMM, split-K4, bx=1: P[z][1600][256] -------------------------
// z: half=z>>1 (0: Z@Wr0t, 1: Zagg@Wnr0t), kc=z&1 -> kStart=kc*512.
// grid (100, 4); block = 16 rows x 256 cols; wave = 16x64 (4 acc chains).
// Named double-buffer register pipeline: consume0/load0+64/consume1/load1+96.
__global__ __launch_bounds__(256) void gemm_l1(
    const float* __restrict__ Z1, const float* __restrict__ Z2,
    const bf16_t* __restrict__ Zah, const bf16_t* __restrict__ Zal,
    const bf16_t* __restrict__ W0h, const bf16_t* __restrict__ W0l,
    float* __restrict__ P) {
  int lane = threadIdx.x & 63;
  int w = threadIdx.x >> 6;
  int jl = lane & 15, hi = lane >> 4;

  int row0 = blockIdx.x * 16;
  int z = blockIdx.y;
  int half = z >> 1;
  int kStart = (z & 1) * 512;
  int r = row0 + jl;

  const size_t WOFF = (size_t)half * 256 * 1024;
  const bf16_t* pBh[4];
  const bf16_t* pBl[4];
  #pragma unroll
  for (int cf = 0; cf < 4; ++cf) {
    int col = w * 64 + cf * 16 + jl;
    pBh[cf] = W0h + WOFF + (size_t)col * 1024 + hi * 8 + kStart;
    pBl[cf] = W0l + WOFF + (size_t)col * 1024 + hi * 8 + kStart;
  }

  f32x4 acc[4] = {};

  if (half == 0) {
    const float* pZ = ((r < N1R) ? Z1 + (size_t)r * VF
                                 : Z2 + (size_t)(r - N1R) * VF) + hi * 8 + kStart;
    float4 za0, zb0, za1, zb1;
    bf16x8 bh0[4], bl0[4], bh1[4], bl1[4];
    za0 = *(const float4*)(pZ + 0);
    zb0 = *(const float4*)(pZ + 4);
    #pragma unroll
    for (int cf = 0; cf < 4; ++cf) {
      bh0[cf] = *(const bf16x8*)(pBh[cf] + 0);
      bl0[cf] = *(const bf16x8*)(pBl[cf] + 0);
    }
    za1 = *(const float4*)(pZ + 32);
    zb1 = *(const float4*)(pZ + 36);
    #pragma unroll
    for (int cf = 0; cf < 4; ++cf) {
      bh1[cf] = *(const bf16x8*)(pBh[cf] + 32);
      bl1[cf] = *(const bf16x8*)(pBl[cf] + 32);
    }
    #pragma unroll 1
    for (int it = 0; it < 7; ++it) {
      int kb = it * 64;
      CONSUME_F32(za0, zb0, bh0, bl0)
      za0 = *(const float4*)(pZ + kb + 64);
      zb0 = *(const float4*)(pZ + kb + 68);
      #pragma unroll
      for (int cf = 0; cf < 4; ++cf) {
        bh0[cf] = *(const bf16x8*)(pBh[cf] + kb + 64);
        bl0[cf] = *(const bf16x8*)(pBl[cf] + kb + 64);
      }
      CONSUME_F32(za1, zb1, bh1, bl1)
      za1 = *(const float4*)(pZ + kb + 96);
      zb1 = *(const float4*)(pZ + kb + 100);
      #pragma unroll
      for (int cf = 0; cf < 4; ++cf) {
        bh1[cf] = *(const bf16x8*)(pBh[cf] + kb + 96);
        bl1[cf] = *(const bf16x8*)(pBl[cf] + kb + 96);
      }
    }
    CONSUME_F32(za0, zb0, bh0, bl0)
    CONSUME_F32(za1, zb1, bh1, bl1)
  } else {
    const bf16_t* pAh = Zah + (size_t)r * VF + hi * 8 + kStart;
    const bf16_t* pAl = Zal + (size_t)r * VF + hi * 8 + kStart;
    bf16x8 ah0, al0, ah1, al1;
    bf16x8 bh0[4], bl0[4], bh1[4], bl1[4];
    ah0 = *(const bf16x8*)(pAh + 0);
    al0 = *(const bf16x8*)(pAl + 0);
    #pragma unroll
    for (int cf = 0; cf < 4; ++cf) {
      bh0[cf] = *(const bf16x8*)(pBh[cf] + 0);
      bl0[cf] = *(const bf16x8*)(pBl[cf] + 0);
    }
    ah1 = *(const bf16x8*)(pAh + 32);
    al1 = *(const bf16x8*)(pAl + 32);
    #pragma unroll
    for (int cf = 0; cf < 4; ++cf) {
      bh1[cf] = *(const bf16x8*)(pBh[cf] + 32);
      bl1[cf] = *(const bf16x8*)(pBl[cf] + 32);
    }
    #pragma unroll 1
    for (int it = 0; it < 7; ++it) {
      int kb = it * 64;
      CONSUME_BF16(ah0, al0, bh0, bl0)
      ah0 = *(const bf16x8*)(pAh + kb + 64);
      al0 = *(const bf16x8*)(pAl + kb + 64);
      #pragma unroll
      for (int cf = 0; cf < 4; ++cf) {
        bh0[cf] = *(const bf16x8*)(pBh[cf] + kb + 64);
        bl0[cf] = *(const bf16x8*)(pBl[cf] + kb + 64);
      }
      CONSUME_BF16(ah1, al1, bh1, bl1)
      ah1 = *(const bf16x8*)(pAh + kb + 96);
      al1 = *(const bf16x8*)(pAl + kb + 96);
      #pragma unroll
      for (int cf = 0; cf < 4; ++cf) {
        bh1[cf] = *(const bf16x8*)(pBh[cf] + kb + 96);
        bl1[cf] = *(const bf16x8*)(pBl[cf] + kb + 96);
      }
    }
    CONSUME_BF16(ah0, al0, bh0, bl0)
    CONSUME_BF16(ah1, al1, bh1, bl1)
  }

  float* Pz = P + (size_t)z * NR * F0;
  #pragma unroll
  for (int cf = 0; cf < 4; ++cf) {
    int col = w * 64 + cf * 16 + jl;
    #pragma unroll
    for (int reg = 0; reg < 4; ++reg) {
      int row = row0 + hi * 4 + reg;
      Pz[(size_t)row * F0 + col] = acc[cf][reg];
    }
  }
}

// ---- agg1 (+combine4): H0 = relu(sum P[0..3]); H0agg = gather(H0)/cnt -----
__global__ void agg1_kernel(const float* __restrict__ P,
                            const int* __restrict__ nb1, const int* __restrict__ nb2,
                            bf16_t* __restrict__ H0h, bf16_t* __restrict__ H0l,
                            bf16_t* __restrict__ Gah, bf16_t* __restrict__ Gal) {
  int r = blockIdx.x;
  int c = threadIdx.x;
  const size_t PS = (size_t)NR * F0;
  const int* nbp;
  int roff;
  if (r < N1R) { nbp = nb1 + r * 10; roff = 0; }
  else         { nbp = nb2 + (r - N1R) * 10; roff = N1R; }
  // own row
  size_t so = (size_t)r * F0 + c;
  float v = fmaxf(P[so] + P[so + PS] + P[so + 2 * PS] + P[so + 3 * PS], 0.f);
  bf16_t h = (bf16_t)v;
  H0h[so] = h;
  H0l[so] = (bf16_t)(v - (float)h);
  // gather
  float s = 0.f; int cnt = 0;
  #pragma unroll
  for (int k = 0; k < 10; ++k) {
    int idx = nbp[k];
    if (idx > -1) {
      cnt++;
      size_t o = (size_t)(roff + idx) * F0 + c;
      s += fmaxf(P[o] + P[o + PS] + P[o + 2 * PS] + P[o + 3 * PS], 0.f);
    }
  }
  float g = s / (float)(cnt > 0 ? cnt : 1);
  bf16_t gh = (bf16_t)g;
  Gah[so] = gh;
  Gal[so] = (bf16_t)(g - (float)gh);
}

// ---- layer-2 GEMM, split-K2, batched: P2[z][1600][128] (f32) --------------
// z=0: H0 @ Wr1t ; z=1: G @ Wnr1t.  grid (2, 100, 2); wave tile 16x16; K=256.
__global__ __launch_bounds__(256) void gemm_l2(
    const bf16_t* __restrict__ H0h, const bf16_t* __restrict__ H0l,
    const bf16_t* __restrict__ Gah, const bf16_t* __restrict__ Gal,
    const bf16_t* __restrict__ W1h, const bf16_t* __restrict__ W1l,
    float* __restrict__ P2) {
  int lane = threadIdx.x & 63;
  int w = threadIdx.x >> 6;
  int jl = lane & 15, hi = lane >> 4;

  int row0 = blockIdx.y * 16;
  int col = blockIdx.x * 64 + w * 16 + jl;
  int z = blockIdx.z;
  int r = row0 + jl;

  const bf16_t* pAh = (z ? Gah : H0h) + (size_t)r * F0 + hi * 8;
  const bf16_t* pAl = (z ? Gal : H0l) + (size_t)r * F0 + hi * 8;
  const size_t WOFF = (size_t)z * 128 * 256;
  const bf16_t* pBh = W1h + WOFF + (size_t)col * 256 + hi * 8;
  const bf16_t* pBl = W1l + WOFF + (size_t)col * 256 + hi * 8;

  f32x4 accE = {}, accO = {};
  for (int kb = 0; kb < 256; kb += 128) {
    bf16x8 ah[4], al[4], bh[4], bl[4];
    #pragma unroll
    for (int u = 0; u < 4; ++u) {
      ah[u] = *(const bf16x8*)(pAh + kb + u * 32);
      al[u] = *(const bf16x8*)(pAl + kb + u * 32);
      bh[u] = *(const bf16x8*)(pBh + kb + u * 32);
      bl[u] = *(const bf16x8*)(pBl + kb + u * 32);
    }
    #pragma unroll
    for (int u = 0; u < 4; ++u) {
      f32x4& acc = (u & 1) ? accO : accE;
      acc = mfma_bf16(ah[u], bh[u], acc);
      acc = mfma_bf16(al[u], bh[u], acc);
      acc = mfma_bf16(ah[u], bl[u], acc);
    }
  }
  float* Pz = P2 + (size_t)z * NR * F1;
  #pragma unroll
  for (int reg = 0; reg < 4; ++reg) {
    int row = row0 + hi * 4 + reg;
    Pz[(size_t)row * F1 + col] = accE[reg] + accO[reg];
  }
}

// ---- dual GEMM (inline combine+relu of P2): ABh = [A'|B] f16 --------------
// h1 = relu(P2_0 + P2_1) built in-register; grid (4, 100); K=128 fully batched.
__global__ __launch_bounds__(256) void gemm_dual(
    const float* __restrict__ P2,
    const bf16_t* __restrict__ fAh, const bf16_t* __restrict__ fAl,
    const bf16_t* __restrict__ fBh, const bf16_t* __restrict__ fBl,
    const float* __restrict__ fb0, f16_t* __restrict__ ABh) {
  int lane = threadIdx.x & 63;
  int w = threadIdx.x >> 6;
  int jl = lane & 15, hi = lane >> 4;

  int row0 = blockIdx.y * 16;
  int col = blockIdx.x * 64 + w * 16 + jl;
  int r = row0 + jl;
  bool isA = (row0 < N1R);

  const float* pP0 = P2 + (size_t)r * F1 + hi * 8;
  const float* pP1 = pP0 + (size_t)NR * F1;
  const bf16_t* pBh = (isA ? fAh : fBh) + (size_t)col * F1 + hi * 8;
  const bf16_t* pBl = (isA ? fAl : fBl) + (size_t)col * F1 + hi * 8;

  // batch the whole K=128: 16 float4 + 8 bf16x8 loads
  float4 p0[4][2], p1[4][2];
  bf16x8 bh[4], bl[4];
  #pragma unroll
  for (int u = 0; u < 4; ++u) {
    p0[u][0] = *(const float4*)(pP0 + u * 32);
    p0[u][1] = *(const float4*)(pP0 + u * 32 + 4);
    p1[u][0] = *(const float4*)(pP1 + u * 32);
    p1[u][1] = *(const float4*)(pP1 + u * 32 + 4);
    bh[u] = *(const bf16x8*)(pBh + u * 32);
    bl[u] = *(const bf16x8*)(pBl + u * 32);
  }
  f32x4 accE = {}, accO = {};
  #pragma unroll
  for (int u = 0; u < 4; ++u) {
    float4 s0 = make_float4(fmaxf(p0[u][0].x + p1[u][0].x, 0.f),
                            fmaxf(p0[u][0].y + p1[u][0].y, 0.f),
                            fmaxf(p0[u][0].z + p1[u][0].z, 0.f),
                            fmaxf(p0[u][0].w + p1[u][0].w, 0.f));
    float4 s1 = make_float4(fmaxf(p0[u][1].x + p1[u][1].x, 0.f),
                            fmaxf(p0[u][1].y + p1[u][1].y, 0.f),
                            fmaxf(p0[u][1].z + p1[u][1].z, 0.f),
                            fmaxf(p0[u][1].w + p1[u][1].w, 0.f));
    bf16x8 ah, al;
    split8(s0, s1, ah, al);
    f32x4& acc = (u & 1) ? accO : accE;
    acc = mfma_bf16(ah, bh[u], acc);
    acc = mfma_bf16(al, bh[u], acc);
    acc = mfma_bf16(ah, bl[u], acc);
  }

  float bv = isA ? fb0[col] : 0.f;
  #pragma unroll
  for (int reg = 0; reg < 4; ++reg) {
    int row = row0 + hi * 4 + reg;
    ABh[(size_t)row * 256 + col] = (f16_t)(accE[reg] + accO[reg] + bv);
  }
}

// ---- pair kernel (FP16, R7/R13-proven): out = fb2+relu(relu(A'+B)@fW1+fb1).fW2
#define IBLK 2
#define ITILE 16
__global__ __launch_bounds__(256) void pair_kernel(
    const f16_t* __restrict__ ABh, const f16_t* __restrict__ W1th,
    const float* __restrict__ fbw, float* __restrict__ out) {
  __shared__ alignas(16) unsigned char sWh[64 * 512];   // [n][512B] swizzled
  __shared__ alignas(16) f16_t sA[ITILE * 256];         // 8KB

  const int tid = threadIdx.x;
  const int lane = tid & 63;
  const int w = tid >> 6;
  const int jl = lane & 15;
  const int hi = lane >> 4;
  const int j0 = blockIdx.x * 64;
  const int i0 = blockIdx.y * ITILE;

  // stage fW1t f16 [64][256] -> LDS, swizzle byte^=((n&7)<<4) in-row
  #pragma unroll
  for (int s = 0; s < 8; ++s) {
    int c = tid + 256 * s;
    int n = c >> 5;
    int cb = (c & 31) << 4;
    int sw = cb ^ ((n & 7) << 4);
    *(uint4*)(sWh + n * 512 + sw) = *(const uint4*)((const unsigned char*)W1th + n * 512 + cb);
  }
  // stage A' rows i0..i0+15 (f16): 512 x 16B chunks, 32 per row
  #pragma unroll
  for (int s = 0; s < 2; ++s) {
    int c = tid + 256 * s;
    int rr = c >> 5;
    int cc = c & 31;
    *(uint4*)((unsigned char*)sA + rr * 512 + cc * 16) =
        *(const uint4*)(ABh + (size_t)(i0 + rr) * 256 + cc * 8);
  }

  // B row of this lane's pair -> registers (its k-slice: 64 f16 = 32 VGPR)
  int j = j0 + w * 16 + jl;
  f16x8 breg[8];
  {
    const f16_t* Bp = ABh + (size_t)(N1R + j) * 256;
    bool ok = (j < N1R);
    f16x8 z{};
    #pragma unroll
    for (int t = 0; t < 8; ++t)
      breg[t] = ok ? *(const f16x8*)(Bp + t * 32 + hi * 8) : z;
  }

  // epilogue constants: 2 vector loads from pre-transposed table
  float4 fb1r = *(const float4*)(fbw + jl * 8);
  float4 fw2r = *(const float4*)(fbw + jl * 8 + 4);
  float bias2 = fbw[128];

  __syncthreads();

  #pragma unroll 1
  for (int ig = 0; ig < ITILE / IBLK; ++ig) {
    f32x4 acc[IBLK][4] = {};
    #pragma unroll
    for (int t = 0; t < 8; ++t) {
      f16x8 bv = breg[t];
      f16x8 af[IBLK];
      const f16x8 Zv{};
      #pragma unroll
      for (int ib = 0; ib < IBLK; ++ib) {
        f16x8 av = *(const f16x8*)(sA + (ig * IBLK + ib) * 256 + t * 32 + hi * 8);
        af[ib] = __builtin_elementwise_max(av + bv, Zv);  // pk_add + pk_max
      }
      int kbyte = t * 64 + hi * 16;
      #pragma unroll
      for (int nf = 0; nf < 4; ++nf) {
        int n = nf * 16 + jl;
        f16x8 wh = *(const f16x8*)(sWh + n * 512 + (kbyte ^ ((n & 7) << 4)));
        #pragma unroll
        for (int ib = 0; ib < IBLK; ++ib)
          acc[ib][nf] = mfma_f16(af[ib], wh, acc[ib][nf]);
      }
    }
    // epilogue: h1 = relu(acc + fb1); out = h1 . fW2 + fb2
    float fb1a[4] = {fb1r.x, fb1r.y, fb1r.z, fb1r.w};
    float fw2a[4] = {fw2r.x, fw2r.y, fw2r.z, fw2r.w};
    #pragma unroll
    for (int ib = 0; ib < IBLK; ++ib) {
      float part[4];
      #pragma unroll
      for (int r = 0; r < 4; ++r) {
        float ssum = 0.f;
        #pragma unroll
        for (int nf = 0; nf < 4; ++nf) {
          float h = acc[ib][nf][r] + fb1a[nf];
          h = fmaxf(h, 0.f);
          ssum += h * fw2a[nf];
        }
        part[r] = ssum;
      }
      #pragma unroll
      for (int off = 1; off < 16; off <<= 1) {
        #pragma unroll
        for (int r = 0; r < 4; ++r) part[r] += __shfl_xor(part[r], off, 64);
      }
      if (jl == 0) {
        int jo = j0 + w * 16 + hi * 4;
        if (jo < N1R) {
          float4 o = make_float4(part[0] + bias2, part[1] + bias2,
                                 part[2] + bias2, part[3] + bias2);
          *(float4*)(out + (size_t)(i0 + ig * IBLK + ib) * 800 + jo) = o;
        }
      }
    }
  }
}

// ---------------------------------------------------------------------------
extern "C" void kernel_launch(void* const* d_in, const int* in_sizes, int n_in,
                              void* d_out, int out_size, void* d_ws, size_t ws_size,
                              hipStream_t stream) {
  const float* Z1   = (const float*)d_in[0];
  const int*   nb1  = (const int*)d_in[1];
  const float* Z2   = (const float*)d_in[2];
  const int*   nb2  = (const int*)d_in[3];
  const float* Wr0  = (const float*)d_in[4];
  const float* Wnr0 = (const float*)d_in[5];
  const float* Wr1  = (const float*)d_in[6];
  const float* Wnr1 = (const float*)d_in[7];
  const float* fW0  = (const float*)d_in[8];
  const float* fb0  = (const float*)d_in[9];
  const float* fW1  = (const float*)d_in[10];
  const float* fb1  = (const float*)d_in[11];
  const float* fW2  = (const float*)d_in[12];
  const float* fb2  = (const float*)d_in[13];
  float* out = (float*)d_out;

  // workspace carve
  char* p = (char*)d_ws;
  auto alloc = [&](size_t bytes) {
    char* q = p;
    p += (bytes + 255) & ~(size_t)255;
    return q;
  };
  bf16_t* W0h   = (bf16_t*)alloc((size_t)512 * 1024 * 2);
  bf16_t* W0l   = (bf16_t*)alloc((size_t)512 * 1024 * 2);
  bf16_t* W1h   = (bf16_t*)alloc((size_t)256 * 256 * 2);
  bf16_t* W1l   = (bf16_t*)alloc((size_t)256 * 256 * 2);
  bf16_t* fAh   = (bf16_t*)alloc((size_t)256 * 128 * 2);
  bf16_t* fAl   = (bf16_t*)alloc((size_t)256 * 128 * 2);
  bf16_t* fBh   = (bf16_t*)alloc((size_t)256 * 128 * 2);
  bf16_t* fBl   = (bf16_t*)alloc((size_t)256 * 128 * 2);
  f16_t*  fW1th = (f16_t*)alloc((size_t)64 * 256 * 2);
  float*  fbw   = (float*)alloc(129 * 4);
  bf16_t* Zah   = (bf16_t*)alloc((size_t)NR * VF * 2);
  bf16_t* Zal   = (bf16_t*)alloc((size_t)NR * VF * 2);
  float*  P01   = (float*)alloc((size_t)4 * NR * F0 * 4);
  bf16_t* H0h   = (bf16_t*)alloc((size_t)NR * F0 * 2);
  bf16_t* H0l   = (bf16_t*)alloc((size_t)NR * F0 * 2);
  bf16_t* Gah   = (bf16_t*)alloc((size_t)NR * F0 * 2);
  bf16_t* Gal   = (bf16_t*)alloc((size_t)NR * F0 * 2);
  float*  P2    = (float*)alloc((size_t)2 * NR * F1 * 4);
  f16_t*  ABh   = (f16_t*)alloc((size_t)NR * 256 * 2);
  (void)in_sizes; (void)n_in; (void)out_size; (void)ws_size;

  // 1. weight conversion + fbw + input-space aggregation (one launch)
  conv_agg<<<4225, 256, 0, stream>>>(Z1, Z2, nb1, nb2, Wr0, Wnr0, Wr1, Wnr1,
                                     fW0, fW1, fb1, fW2, fb2,
                                     W0h, W0l, W1h, W1l, fAh, fAl, fBh, fBl,
                                     fW1th, fbw, Zah, Zal);
  // 2. layer-1 split-K4 GEMM (bx=1, Z read once) -> partials P[4][1600][256]
  gemm_l1<<<dim3(100, 4), 256, 0, stream>>>(Z1, Z2, Zah, Zal, W0h, W0l, P01);
  // 3. combine4 + relu + H0 aggregation (one launch)
  agg1_kernel<<<NR, 256, 0, stream>>>(P01, nb1, nb2, H0h, H0l, Gah, Gal);
  // 4. layer-2 split-K2 GEMM -> partials P2[2][1600][128]
  gemm_l2<<<dim3(2, 100, 2), 256, 0, stream>>>(H0h, H0l, Gah, Gal, W1h, W1l, P2);
  // 5. dual GEMM (inline combine+relu) -> ABh f16
  gemm_dual<<<dim3(4, 100), 256, 0, stream>>>(P2, fAh, fAl, fBh, fBl, fb0, ABh);
  // 6. all-pairs fused MLP (fp16 datapath)
  pair_kernel<<<dim3(13, 50), 256, 0, stream>>>(ABh, fW1th, fbw, out);
}